// Round 1
// baseline (3358.471 us; speedup 1.0000x reference)
//
#include <hip/hip_runtime.h>

#define NCLS 8
#define NPT  2048
#define DIM  64
#define FINF 3.402823466e38f

// ---------------------------------------------------------------------------
// Kernel 1: per-row squared norms. One wave (64 lanes) per row, DIM==64.
// ---------------------------------------------------------------------------
__global__ void row_norms_kernel(const float* __restrict__ x, float* __restrict__ sq) {
    int row  = blockIdx.x * 4 + (threadIdx.x >> 6);
    int lane = threadIdx.x & 63;
    float v = x[(size_t)row * DIM + lane];
    float s = v * v;
    #pragma unroll
    for (int m = 32; m >= 1; m >>= 1) s += __shfl_xor(s, m);
    if (lane == 0) sq[row] = s;
}

// ---------------------------------------------------------------------------
// Kernel 2: dense distance matrix per class via Gram identity (matches ref):
//   d2 = max(sq_i + sq_j - 2*dot(x_i,x_j), 0);  d = d2 > 0 ? sqrt(d2) : 0
// 64x64 output tile per 256-thread WG, 4x4 micro-tile per thread, K=64 in LDS.
// ---------------------------------------------------------------------------
__global__ __launch_bounds__(256) void dist_kernel(const float* __restrict__ x,
                                                   const float* __restrict__ sq,
                                                   float* __restrict__ dist) {
    __shared__ float As[64][68];   // As[row][k]   (broadcast reads)
    __shared__ float Bs[64][68];   // Bs[k][col]   (vector float4 reads)
    const int c   = blockIdx.z;
    const int ti  = blockIdx.y;
    const int tj  = blockIdx.x;
    const int tid = threadIdx.x;

    const float4* x4 = (const float4*)(x + (size_t)c * NPT * DIM);

    #pragma unroll
    for (int it = 0; it < 4; ++it) {
        int q   = it * 256 + tid;
        int row = q >> 4;         // 0..63 within tile
        int c4  = q & 15;         // float4 index along k
        float4 va = x4[(size_t)(ti * 64 + row) * 16 + c4];
        *(float4*)&As[row][c4 * 4] = va;
        float4 vb = x4[(size_t)(tj * 64 + row) * 16 + c4];
        Bs[c4 * 4 + 0][row] = vb.x;
        Bs[c4 * 4 + 1][row] = vb.y;
        Bs[c4 * 4 + 2][row] = vb.z;
        Bs[c4 * 4 + 3][row] = vb.w;
    }
    __syncthreads();

    const int tx = tid & 15;   // col group
    const int ty = tid >> 4;   // row group
    float acc[4][4] = {};
    #pragma unroll
    for (int k = 0; k < 64; ++k) {
        float4 b4 = *(const float4*)&Bs[k][tx * 4];
        #pragma unroll
        for (int i = 0; i < 4; ++i) {
            float a = As[ty * 4 + i][k];
            acc[i][0] = fmaf(a, b4.x, acc[i][0]);
            acc[i][1] = fmaf(a, b4.y, acc[i][1]);
            acc[i][2] = fmaf(a, b4.z, acc[i][2]);
            acc[i][3] = fmaf(a, b4.w, acc[i][3]);
        }
    }

    const float* sqc = sq + (size_t)c * NPT;
    float sqb[4];
    #pragma unroll
    for (int j = 0; j < 4; ++j) sqb[j] = sqc[tj * 64 + tx * 4 + j];

    #pragma unroll
    for (int i = 0; i < 4; ++i) {
        float sqa = sqc[ti * 64 + ty * 4 + i];
        float o[4];
        #pragma unroll
        for (int j = 0; j < 4; ++j) {
            float d2 = sqa + sqb[j] - 2.0f * acc[i][j];
            d2 = d2 > 0.0f ? d2 : 0.0f;
            o[j] = d2 > 0.0f ? sqrtf(d2) : 0.0f;
        }
        float4 ov = make_float4(o[0], o[1], o[2], o[3]);
        *(float4*)(dist + ((size_t)c * NPT + ti * 64 + ty * 4 + i) * NPT
                        + tj * 64 + tx * 4) = ov;
    }
}

// ---------------------------------------------------------------------------
// Kernel 3: Prim's MST per class. One 1024-thread WG per class; each thread
// owns vertices 2*tid, 2*tid+1 with mind[] kept in registers. Edge lengths
// are the extraction-time mind values; loss accumulated on thread 0.
// ONFLY=true computes distances on demand (fallback when ws is too small).
// ---------------------------------------------------------------------------
template <bool ONFLY>
__global__ __launch_bounds__(1024) void prim_kernel(const float* __restrict__ x,
                                                    const float* __restrict__ dist,
                                                    float* __restrict__ loss_out) {
    __shared__ float  redV[2][16];
    __shared__ int    redI[2][16];
    __shared__ float  finV[2];
    __shared__ int    finI[2];
    __shared__ float4 xjs[2][16];

    const int c    = blockIdx.x;
    const int tid  = threadIdx.x;
    const int lane = tid & 63;
    const int wid  = tid >> 6;
    const int v0   = tid * 2;
    const int v1   = tid * 2 + 1;

    float m0 = FINF, m1 = FINF;
    bool  t0 = (v0 == 0);   // vertex 0 starts in tree
    bool  t1 = false;

    int   j = 0;
    int   p = 0;
    float loss = 0.0f;

    const float*  distc = ONFLY ? nullptr : (dist + (size_t)c * NPT * NPT);
    const float4* xc4   = (const float4*)(x + (size_t)c * NPT * DIM);

    for (int t = 0; t < NPT - 1; ++t) {
        float d0, d1;
        if (ONFLY) {
            if (tid < 16) xjs[p][tid] = xc4[(size_t)j * 16 + tid];
            __syncthreads();
            float a0 = 0.0f, a1 = 0.0f;
            #pragma unroll
            for (int k = 0; k < 16; ++k) {
                float4 xj = xjs[p][k];
                float4 q0 = xc4[(size_t)v0 * 16 + k];
                float4 q1 = xc4[(size_t)v1 * 16 + k];
                float dx;
                dx = xj.x - q0.x; a0 = fmaf(dx, dx, a0);
                dx = xj.y - q0.y; a0 = fmaf(dx, dx, a0);
                dx = xj.z - q0.z; a0 = fmaf(dx, dx, a0);
                dx = xj.w - q0.w; a0 = fmaf(dx, dx, a0);
                dx = xj.x - q1.x; a1 = fmaf(dx, dx, a1);
                dx = xj.y - q1.y; a1 = fmaf(dx, dx, a1);
                dx = xj.z - q1.z; a1 = fmaf(dx, dx, a1);
                dx = xj.w - q1.w; a1 = fmaf(dx, dx, a1);
            }
            d0 = a0 > 0.0f ? sqrtf(a0) : 0.0f;
            d1 = a1 > 0.0f ? sqrtf(a1) : 0.0f;
        } else {
            float2 r = ((const float2*)(distc + (size_t)j * NPT))[tid];
            d0 = r.x;
            d1 = r.y;
        }

        if (!t0) m0 = fminf(m0, d0);
        if (!t1) m1 = fminf(m1, d1);

        // local argmin over the two owned vertices (tie -> smaller index)
        float val; int idx;
        if (m0 <= m1) { val = m0; idx = v0; }
        else          { val = m1; idx = v1; }

        // wave-level argmin
        #pragma unroll
        for (int m = 32; m >= 1; m >>= 1) {
            float ov = __shfl_xor(val, m);
            int   oi = __shfl_xor(idx, m);
            if (ov < val || (ov == val && oi < idx)) { val = ov; idx = oi; }
        }
        if (lane == 0) { redV[p][wid] = val; redI[p][wid] = idx; }
        __syncthreads();

        // cross-wave argmin on wave 0
        if (wid == 0) {
            float v  = (lane < 16) ? redV[p][lane] : FINF;
            int   i2 = (lane < 16) ? redI[p][lane] : 0x7fffffff;
            #pragma unroll
            for (int m = 8; m >= 1; m >>= 1) {
                float ov = __shfl_xor(v, m);
                int   oi = __shfl_xor(i2, m);
                if (ov < v || (ov == v && oi < i2)) { v = ov; i2 = oi; }
            }
            if (lane == 0) { finV[p] = v; finI[p] = i2; }
        }
        __syncthreads();

        float bv = finV[p];
        j        = finI[p];
        if (tid == 0) loss += fabsf(bv - 1.0f);
        if (v0 == j) { t0 = true; m0 = FINF; }
        if (v1 == j) { t1 = true; m1 = FINF; }
        p ^= 1;
    }

    if (tid == 0) loss_out[c] = loss / (float)(NPT - 1);
}

// ---------------------------------------------------------------------------
// Kernel 4: deterministic fixed-order final sum over the 8 class losses.
// ---------------------------------------------------------------------------
__global__ void finalize_kernel(const float* __restrict__ loss, float* __restrict__ out) {
    if (threadIdx.x == 0 && blockIdx.x == 0) {
        float s = 0.0f;
        for (int c = 0; c < NCLS; ++c) s += loss[c];
        out[0] = s;
    }
}

extern "C" void kernel_launch(void* const* d_in, const int* in_sizes, int n_in,
                              void* d_out, int out_size, void* d_ws, size_t ws_size,
                              hipStream_t stream) {
    const float* x   = (const float*)d_in[0];
    float*       out = (float*)d_out;

    const size_t distElems = (size_t)NCLS * NPT * NPT;
    const size_t sqElems   = (size_t)NCLS * NPT;
    const size_t need      = distElems * sizeof(float) + sqElems * sizeof(float)
                           + NCLS * sizeof(float);

    if (ws_size >= need) {
        float* dist = (float*)d_ws;
        float* sq   = dist + distElems;
        float* loss = sq + sqElems;
        row_norms_kernel<<<(NCLS * NPT) / 4, 256, 0, stream>>>(x, sq);
        dist_kernel<<<dim3(NPT / 64, NPT / 64, NCLS), 256, 0, stream>>>(x, sq, dist);
        prim_kernel<false><<<NCLS, 1024, 0, stream>>>(x, dist, loss);
        finalize_kernel<<<1, 64, 0, stream>>>(loss, out);
    } else {
        float* loss = (float*)d_ws;   // needs only 32 bytes
        prim_kernel<true><<<NCLS, 1024, 0, stream>>>(x, nullptr, loss);
        finalize_kernel<<<1, 64, 0, stream>>>(loss, out);
    }
}

// Round 2
// 2282.173 us; speedup vs baseline: 1.4716x; 1.4716x over previous
//
#include <hip/hip_runtime.h>

#define NCLS 8
#define NPT  2048
#define DIM  64
#define FINF 3.402823466e38f
#define INFK 0xFFFFFFFFu

// ---------------------------------------------------------------------------
// Kernel 1: per-row squared norms. One wave (64 lanes) per row, DIM==64.
// ---------------------------------------------------------------------------
__global__ void row_norms_kernel(const float* __restrict__ x, float* __restrict__ sq) {
    int row  = blockIdx.x * 4 + (threadIdx.x >> 6);
    int lane = threadIdx.x & 63;
    float v = x[(size_t)row * DIM + lane];
    float s = v * v;
    #pragma unroll
    for (int m = 32; m >= 1; m >>= 1) s += __shfl_xor(s, m);
    if (lane == 0) sq[row] = s;
}

// ---------------------------------------------------------------------------
// Kernel 2: packed-key distance matrix per class via Gram identity.
// key = (float_bits(d) rounded to 21 bits) | col_index  (11 low bits).
// Diagonal -> INFK so self-distance never wins the argmin.
// 64x64 tile per 256-thread WG, 4x4 micro-tile per thread, K=64 in LDS.
// ---------------------------------------------------------------------------
__global__ __launch_bounds__(256) void distkey_kernel(const float* __restrict__ x,
                                                      const float* __restrict__ sq,
                                                      unsigned int* __restrict__ dist) {
    __shared__ float As[64][68];   // As[row][k]
    __shared__ float Bs[64][68];   // Bs[k][col]
    const int c   = blockIdx.z;
    const int ti  = blockIdx.y;
    const int tj  = blockIdx.x;
    const int tid = threadIdx.x;

    const float4* x4 = (const float4*)(x + (size_t)c * NPT * DIM);

    #pragma unroll
    for (int it = 0; it < 4; ++it) {
        int q   = it * 256 + tid;
        int row = q >> 4;
        int c4  = q & 15;
        float4 va = x4[(size_t)(ti * 64 + row) * 16 + c4];
        *(float4*)&As[row][c4 * 4] = va;
        float4 vb = x4[(size_t)(tj * 64 + row) * 16 + c4];
        Bs[c4 * 4 + 0][row] = vb.x;
        Bs[c4 * 4 + 1][row] = vb.y;
        Bs[c4 * 4 + 2][row] = vb.z;
        Bs[c4 * 4 + 3][row] = vb.w;
    }
    __syncthreads();

    const int tx = tid & 15;
    const int ty = tid >> 4;
    float acc[4][4] = {};
    #pragma unroll
    for (int k = 0; k < 64; ++k) {
        float4 b4 = *(const float4*)&Bs[k][tx * 4];
        #pragma unroll
        for (int i = 0; i < 4; ++i) {
            float a = As[ty * 4 + i][k];
            acc[i][0] = fmaf(a, b4.x, acc[i][0]);
            acc[i][1] = fmaf(a, b4.y, acc[i][1]);
            acc[i][2] = fmaf(a, b4.z, acc[i][2]);
            acc[i][3] = fmaf(a, b4.w, acc[i][3]);
        }
    }

    const float* sqc = sq + (size_t)c * NPT;
    float sqb[4];
    #pragma unroll
    for (int j = 0; j < 4; ++j) sqb[j] = sqc[tj * 64 + tx * 4 + j];

    #pragma unroll
    for (int i = 0; i < 4; ++i) {
        int rowg = ti * 64 + ty * 4 + i;
        float sqa = sqc[rowg];
        unsigned int o[4];
        #pragma unroll
        for (int j = 0; j < 4; ++j) {
            int colg = tj * 64 + tx * 4 + j;
            float d2 = sqa + sqb[j] - 2.0f * acc[i][j];
            d2 = d2 > 0.0f ? d2 : 0.0f;
            float d = d2 > 0.0f ? sqrtf(d2) : 0.0f;
            unsigned int b = __float_as_uint(d);
            b = (b + 0x400u) & 0xFFFFF800u;            // round-to-nearest 21-bit value
            o[j] = (rowg == colg) ? INFK : (b | (unsigned int)colg);
        }
        uint4 ov = make_uint4(o[0], o[1], o[2], o[3]);
        *(uint4*)(dist + ((size_t)c * NPT + rowg) * NPT + tj * 64 + tx * 4) = ov;
    }
}

// ---------------------------------------------------------------------------
// Kernel 3: single-wave register Prim per class. Lane l owns 32 vertices in
// registers; slot (k,e) <-> vertex u = k*256 + l*4 + e (matches the dwordx4
// fetch layout). No barriers, no LDS. msk[s] = 0xFFFFFFFF once in-tree.
// ---------------------------------------------------------------------------
__global__ __launch_bounds__(64) void prim2_kernel(const unsigned int* __restrict__ dist,
                                                   float* __restrict__ loss_out) {
    const int c    = blockIdx.x;
    const int lane = threadIdx.x;
    const unsigned int* distc = dist + (size_t)c * NPT * NPT;

    unsigned int m[32], msk[32];
    #pragma unroll
    for (int s = 0; s < 32; ++s) { m[s] = INFK; msk[s] = 0u; }
    // vertex 0 starts in tree: owner lane 0, slot 0.
    msk[0] = (lane == 0) ? INFK : 0u;

    int   j    = 0;
    float loss = 0.0f;

    // prologue: issue loads for row 0
    const uint4* rowp = (const uint4*)distc;
    uint4 r[8];
    #pragma unroll
    for (int k = 0; k < 8; ++k) r[k] = rowp[k * 64 + lane];

    for (int t = 0; t < NPT - 1; ++t) {
        // min-update with fetched row (masked OR keeps in-tree slots at INFK)
        #pragma unroll
        for (int k = 0; k < 8; ++k) {
            m[k*4+0] = min(m[k*4+0], r[k].x | msk[k*4+0]);
            m[k*4+1] = min(m[k*4+1], r[k].y | msk[k*4+1]);
            m[k*4+2] = min(m[k*4+2], r[k].z | msk[k*4+2]);
            m[k*4+3] = min(m[k*4+3], r[k].w | msk[k*4+3]);
        }

        // per-lane min tree then wave butterfly min (key carries vertex idx)
        unsigned int best = m[0];
        #pragma unroll
        for (int s = 1; s < 32; ++s) best = min(best, m[s]);
        #pragma unroll
        for (int w = 32; w >= 1; w >>= 1)
            best = min(best, (unsigned int)__shfl_xor((int)best, w));

        int bj = __builtin_amdgcn_readfirstlane((int)best);
        j = bj & 0x7FF;
        loss += fabsf(__uint_as_float((unsigned int)bj & 0xFFFFF800u) - 1.0f);

        // issue next row's loads immediately (clear hides under the latency)
        const uint4* nrp = (const uint4*)(distc + (size_t)j * NPT);
        #pragma unroll
        for (int k = 0; k < 8; ++k) r[k] = nrp[k * 64 + lane];

        // mark j in-tree: owner lane clears its slot
        int sl = ((j >> 8) << 2) | (j & 3);
        int ln = (j >> 2) & 63;
        bool own = (lane == ln);
        #pragma unroll
        for (int s = 0; s < 32; ++s) {
            if (s == sl) {
                m[s]   = own ? INFK : m[s];
                msk[s] = own ? INFK : msk[s];
            }
        }
    }

    if (lane == 0) loss_out[c] = loss * (1.0f / (float)(NPT - 1));
}

// ---------------------------------------------------------------------------
// Fallback (ws too small): on-the-fly Prim, 1024 threads/class (round-1 code).
// ---------------------------------------------------------------------------
__global__ __launch_bounds__(1024) void prim_onfly_kernel(const float* __restrict__ x,
                                                          float* __restrict__ loss_out) {
    __shared__ float  redV[2][16];
    __shared__ int    redI[2][16];
    __shared__ float  finV[2];
    __shared__ int    finI[2];
    __shared__ float4 xjs[2][16];

    const int c    = blockIdx.x;
    const int tid  = threadIdx.x;
    const int lane = tid & 63;
    const int wid  = tid >> 6;
    const int v0   = tid * 2;
    const int v1   = tid * 2 + 1;

    float m0 = FINF, m1 = FINF;
    bool  t0 = (v0 == 0);
    bool  t1 = false;

    int   j = 0;
    int   p = 0;
    float loss = 0.0f;

    const float4* xc4 = (const float4*)(x + (size_t)c * NPT * DIM);

    for (int t = 0; t < NPT - 1; ++t) {
        if (tid < 16) xjs[p][tid] = xc4[(size_t)j * 16 + tid];
        __syncthreads();
        float a0 = 0.0f, a1 = 0.0f;
        #pragma unroll
        for (int k = 0; k < 16; ++k) {
            float4 xj = xjs[p][k];
            float4 q0 = xc4[(size_t)v0 * 16 + k];
            float4 q1 = xc4[(size_t)v1 * 16 + k];
            float dx;
            dx = xj.x - q0.x; a0 = fmaf(dx, dx, a0);
            dx = xj.y - q0.y; a0 = fmaf(dx, dx, a0);
            dx = xj.z - q0.z; a0 = fmaf(dx, dx, a0);
            dx = xj.w - q0.w; a0 = fmaf(dx, dx, a0);
            dx = xj.x - q1.x; a1 = fmaf(dx, dx, a1);
            dx = xj.y - q1.y; a1 = fmaf(dx, dx, a1);
            dx = xj.z - q1.z; a1 = fmaf(dx, dx, a1);
            dx = xj.w - q1.w; a1 = fmaf(dx, dx, a1);
        }
        float d0 = a0 > 0.0f ? sqrtf(a0) : 0.0f;
        float d1 = a1 > 0.0f ? sqrtf(a1) : 0.0f;

        if (!t0) m0 = fminf(m0, d0);
        if (!t1) m1 = fminf(m1, d1);

        float val; int idx;
        if (m0 <= m1) { val = m0; idx = v0; }
        else          { val = m1; idx = v1; }

        #pragma unroll
        for (int m = 32; m >= 1; m >>= 1) {
            float ov = __shfl_xor(val, m);
            int   oi = __shfl_xor(idx, m);
            if (ov < val || (ov == val && oi < idx)) { val = ov; idx = oi; }
        }
        if (lane == 0) { redV[p][wid] = val; redI[p][wid] = idx; }
        __syncthreads();

        if (wid == 0) {
            float v  = (lane < 16) ? redV[p][lane] : FINF;
            int   i2 = (lane < 16) ? redI[p][lane] : 0x7fffffff;
            #pragma unroll
            for (int m = 8; m >= 1; m >>= 1) {
                float ov = __shfl_xor(v, m);
                int   oi = __shfl_xor(i2, m);
                if (ov < v || (ov == v && oi < i2)) { v = ov; i2 = oi; }
            }
            if (lane == 0) { finV[p] = v; finI[p] = i2; }
        }
        __syncthreads();

        float bv = finV[p];
        j        = finI[p];
        if (tid == 0) loss += fabsf(bv - 1.0f);
        if (v0 == j) { t0 = true; m0 = FINF; }
        if (v1 == j) { t1 = true; m1 = FINF; }
        p ^= 1;
    }

    if (tid == 0) loss_out[c] = loss / (float)(NPT - 1);
}

// ---------------------------------------------------------------------------
// Kernel 4: deterministic fixed-order final sum over the 8 class losses.
// ---------------------------------------------------------------------------
__global__ void finalize_kernel(const float* __restrict__ loss, float* __restrict__ out) {
    if (threadIdx.x == 0 && blockIdx.x == 0) {
        float s = 0.0f;
        for (int c = 0; c < NCLS; ++c) s += loss[c];
        out[0] = s;
    }
}

extern "C" void kernel_launch(void* const* d_in, const int* in_sizes, int n_in,
                              void* d_out, int out_size, void* d_ws, size_t ws_size,
                              hipStream_t stream) {
    const float* x   = (const float*)d_in[0];
    float*       out = (float*)d_out;

    const size_t distElems = (size_t)NCLS * NPT * NPT;
    const size_t sqElems   = (size_t)NCLS * NPT;
    const size_t need      = distElems * sizeof(unsigned int)
                           + sqElems * sizeof(float) + NCLS * sizeof(float);

    if (ws_size >= need) {
        unsigned int* dist = (unsigned int*)d_ws;
        float*        sq   = (float*)(dist + distElems);
        float*        loss = sq + sqElems;
        row_norms_kernel<<<(NCLS * NPT) / 4, 256, 0, stream>>>(x, sq);
        distkey_kernel<<<dim3(NPT / 64, NPT / 64, NCLS), 256, 0, stream>>>(x, sq, dist);
        prim2_kernel<<<NCLS, 64, 0, stream>>>(dist, loss);
        finalize_kernel<<<1, 64, 0, stream>>>(loss, out);
    } else {
        float* loss = (float*)d_ws;
        prim_onfly_kernel<<<NCLS, 1024, 0, stream>>>(x, loss);
        finalize_kernel<<<1, 64, 0, stream>>>(loss, out);
    }
}

// Round 3
// 357.757 us; speedup vs baseline: 9.3876x; 6.3791x over previous
//
#include <hip/hip_runtime.h>

#define NCLS 8
#define NPT  2048
#define DIM  64
#define FINF 3.402823466e38f
#define INFK 0xFFFFFFFFu
#define INF64 0xFFFFFFFFFFFFFFFFull

typedef unsigned int u32;
typedef unsigned long long u64;

// ---------------------------------------------------------------------------
// Kernel 1: per-row squared norms. One wave (64 lanes) per row, DIM==64.
// ---------------------------------------------------------------------------
__global__ void row_norms_kernel(const float* __restrict__ x, float* __restrict__ sq) {
    int row  = blockIdx.x * 4 + (threadIdx.x >> 6);
    int lane = threadIdx.x & 63;
    float v = x[(size_t)row * DIM + lane];
    float s = v * v;
    #pragma unroll
    for (int m = 32; m >= 1; m >>= 1) s += __shfl_xor(s, m);
    if (lane == 0) sq[row] = s;
}

// ---------------------------------------------------------------------------
// Init: comp[v]=v, minEdge=INF, lossAcc=0, classDone=0.
// ---------------------------------------------------------------------------
__global__ void init_kernel(u32* __restrict__ comp, u64* __restrict__ minEdge,
                            float* __restrict__ lossAcc, u32* __restrict__ classDone) {
    int i = blockIdx.x * 256 + threadIdx.x;
    if (i < NCLS * NPT) {
        comp[i]    = (u32)(i & (NPT - 1));
        minEdge[i] = INF64;
    }
    if (i < NCLS) { lossAcc[i] = 0.0f; classDone[i] = 0u; }
}

// ---------------------------------------------------------------------------
// Kernel 2: packed-key distance matrix + Boruvka round-1 row-min folded in.
// key = (float_bits(d) rounded to 21 bits) | col_index (11 low bits).
// Round-1 minEdge[v] via per-tile row-min + global atomicMin(u64).
// ---------------------------------------------------------------------------
__global__ __launch_bounds__(256) void distkey_kernel(const float* __restrict__ x,
                                                      const float* __restrict__ sq,
                                                      u32* __restrict__ dist,
                                                      u64* __restrict__ minEdge) {
    __shared__ float As[64][68];
    __shared__ float Bs[64][68];
    const int c   = blockIdx.z;
    const int ti  = blockIdx.y;
    const int tj  = blockIdx.x;
    const int tid = threadIdx.x;

    const float4* x4 = (const float4*)(x + (size_t)c * NPT * DIM);

    #pragma unroll
    for (int it = 0; it < 4; ++it) {
        int q   = it * 256 + tid;
        int row = q >> 4;
        int c4  = q & 15;
        float4 va = x4[(size_t)(ti * 64 + row) * 16 + c4];
        *(float4*)&As[row][c4 * 4] = va;
        float4 vb = x4[(size_t)(tj * 64 + row) * 16 + c4];
        Bs[c4 * 4 + 0][row] = vb.x;
        Bs[c4 * 4 + 1][row] = vb.y;
        Bs[c4 * 4 + 2][row] = vb.z;
        Bs[c4 * 4 + 3][row] = vb.w;
    }
    __syncthreads();

    const int tx = tid & 15;
    const int ty = tid >> 4;
    float acc[4][4] = {};
    #pragma unroll
    for (int k = 0; k < 64; ++k) {
        float4 b4 = *(const float4*)&Bs[k][tx * 4];
        #pragma unroll
        for (int i = 0; i < 4; ++i) {
            float a = As[ty * 4 + i][k];
            acc[i][0] = fmaf(a, b4.x, acc[i][0]);
            acc[i][1] = fmaf(a, b4.y, acc[i][1]);
            acc[i][2] = fmaf(a, b4.z, acc[i][2]);
            acc[i][3] = fmaf(a, b4.w, acc[i][3]);
        }
    }

    const float* sqc = sq + (size_t)c * NPT;
    float sqb[4];
    #pragma unroll
    for (int j = 0; j < 4; ++j) sqb[j] = sqc[tj * 64 + tx * 4 + j];

    #pragma unroll
    for (int i = 0; i < 4; ++i) {
        int rowg = ti * 64 + ty * 4 + i;
        float sqa = sqc[rowg];
        u32 o[4];
        #pragma unroll
        for (int j = 0; j < 4; ++j) {
            int colg = tj * 64 + tx * 4 + j;
            float d2 = sqa + sqb[j] - 2.0f * acc[i][j];
            d2 = d2 > 0.0f ? d2 : 0.0f;
            float d = d2 > 0.0f ? sqrtf(d2) : 0.0f;
            u32 b = __float_as_uint(d);
            b = (b + 0x400u) & 0xFFFFF800u;   // round-to-nearest 21-bit value
            o[j] = (rowg == colg) ? INFK : (b | (u32)colg);
        }
        uint4 ov = make_uint4(o[0], o[1], o[2], o[3]);
        *(uint4*)(dist + ((size_t)c * NPT + rowg) * NPT + tj * 64 + tx * 4) = ov;

        // ---- Boruvka round 1: per-tile row-min -> atomicMin per row ----
        u32 bm = min(min(o[0], o[1]), min(o[2], o[3]));
        #pragma unroll
        for (int m = 8; m >= 1; m >>= 1)
            bm = min(bm, (u32)__shfl_xor((int)bm, m));
        if (tx == 0 && bm != INFK) {
            int j2 = (int)(bm & 0x7FF);
            u32 db = bm >> 11;
            int mn = rowg < j2 ? rowg : j2;
            int mx = rowg < j2 ? j2 : rowg;
            u64 key = ((u64)db << 22) | ((u64)mn << 11) | (u64)mx;
            atomicMin(&minEdge[(size_t)c * NPT + rowg], key);
        }
    }
}

// ---------------------------------------------------------------------------
// Kernel 3: Boruvka scan round. Each wave scans rows; per row: min packed key
// over columns whose comp differs from the row's comp; atomicMin into the
// row's component slot with a strictly-ordered u64 edge key (d, min, max).
// ---------------------------------------------------------------------------
__global__ __launch_bounds__(256) void scan_kernel(const u32* __restrict__ dist,
                                                   const u32* __restrict__ comp,
                                                   u64* __restrict__ minEdge,
                                                   const u32* __restrict__ classDone) {
    __shared__ u32 compL[NPT];
    const int c = blockIdx.y;
    if (classDone[c]) return;
    const int tid  = threadIdx.x;
    const int lane = tid & 63;
    const int wid  = tid >> 6;

    const u32* compG = comp + (size_t)c * NPT;
    #pragma unroll
    for (int k = 0; k < NPT / 256; ++k) compL[k * 256 + tid] = compG[k * 256 + tid];
    __syncthreads();

    const u32* distc = dist + (size_t)c * NPT * NPT;

    #pragma unroll 1
    for (int rr = 0; rr < 8; ++rr) {
        int v = blockIdx.x * 32 + wid * 8 + rr;
        u32 myc = compL[v];
        const uint4* rp = (const uint4*)(distc + (size_t)v * NPT);
        u32 best = INFK;
        #pragma unroll
        for (int k = 0; k < 8; ++k) {
            uint4 r  = rp[k * 64 + lane];
            uint4 cq = *(const uint4*)&compL[(k * 64 + lane) * 4];
            u32 s0 = (cq.x == myc) ? INFK : r.x;
            u32 s1 = (cq.y == myc) ? INFK : r.y;
            u32 s2 = (cq.z == myc) ? INFK : r.z;
            u32 s3 = (cq.w == myc) ? INFK : r.w;
            best = min(best, min(min(s0, s1), min(s2, s3)));
        }
        #pragma unroll
        for (int m = 32; m >= 1; m >>= 1)
            best = min(best, (u32)__shfl_xor((int)best, m));
        if (lane == 0 && best != INFK) {
            int j  = (int)(best & 0x7FF);
            u32 db = best >> 11;
            int mn = v < j ? v : j;
            int mx = v < j ? j : v;
            u64 key = ((u64)db << 22) | ((u64)mn << 11) | (u64)mx;
            atomicMin(&minEdge[(size_t)c * NPT + myc], key);
        }
    }
}

// ---------------------------------------------------------------------------
// Kernel 4: Boruvka merge. One block per class: hook each root to its min
// outgoing edge's target component (mutual pairs dedup'd by L>O), accumulate
// |d-1| once per accepted edge, pointer-jump to compress, update comp[],
// reset minEdge, detect convergence.
// ---------------------------------------------------------------------------
__global__ __launch_bounds__(256) void merge_kernel(u32* __restrict__ comp,
                                                    u64* __restrict__ minEdge,
                                                    float* __restrict__ lossAcc,
                                                    u32* __restrict__ classDone) {
    __shared__ u32  compL[NPT];
    __shared__ u32  parentL[NPT];
    __shared__ u64  edgeL[NPT];
    __shared__ float rw[256];
    __shared__ int   rc[256];
    __shared__ int   conv;

    const int c   = blockIdx.x;
    const int tid = threadIdx.x;
    if (classDone[c]) return;

    u32* compG = comp + (size_t)c * NPT;
    u64* edgeG = minEdge + (size_t)c * NPT;

    #pragma unroll
    for (int k = 0; k < NPT / 256; ++k) {
        int i = k * 256 + tid;
        compL[i]   = compG[i];
        parentL[i] = (u32)i;
        edgeL[i]   = edgeG[i];
    }
    if (tid == 0) conv = 1;
    __syncthreads();

    float myw = 0.0f;
    int   mycnt = 0;
    #pragma unroll
    for (int k = 0; k < NPT / 256; ++k) {
        int L = k * 256 + tid;
        u64 e = edgeL[L];
        if (e != INF64) {
            int mn = (int)((e >> 11) & 0x7FF);
            int mx = (int)(e & 0x7FF);
            u32 A = compL[mn], B = compL[mx];
            u32 O = (A == (u32)L) ? B : A;
            bool mutual = (edgeL[O] == e);
            if (!(mutual && (u32)L > O)) {
                parentL[L] = O;
                u32 dbits = (u32)(e >> 22);
                float d = __uint_as_float(dbits << 11);
                myw += fabsf(d - 1.0f);
                mycnt += 1;
            }
        }
    }
    __syncthreads();

    // pointer jumping: 11 doublings cover chains up to length 2048
    for (int it = 0; it < 11; ++it) {
        u32 np[NPT / 256];
        #pragma unroll
        for (int k = 0; k < NPT / 256; ++k) {
            int L = k * 256 + tid;
            np[k] = parentL[parentL[L]];
        }
        __syncthreads();
        #pragma unroll
        for (int k = 0; k < NPT / 256; ++k) parentL[k * 256 + tid] = np[k];
        __syncthreads();
    }

    u32 root0 = parentL[compL[0]];
    #pragma unroll
    for (int k = 0; k < NPT / 256; ++k) {
        int v = k * 256 + tid;
        u32 nc = parentL[compL[v]];
        compG[v] = nc;
        if (nc != root0) conv = 0;     // benign race: all writers write 0
        edgeG[v] = INF64;              // reset for next round
    }

    rw[tid] = myw; rc[tid] = mycnt;
    __syncthreads();
    for (int s = 128; s >= 1; s >>= 1) {
        if (tid < s) { rw[tid] += rw[tid + s]; rc[tid] += rc[tid + s]; }
        __syncthreads();
    }
    if (tid == 0) {
        lossAcc[c] += rw[0];
        if (conv || rc[0] == 0) classDone[c] = 1;
    }
}

// ---------------------------------------------------------------------------
// Finalize: out = sum_c lossAcc[c] / (NPT-1).
// ---------------------------------------------------------------------------
__global__ void final2_kernel(const float* __restrict__ lossAcc, float* __restrict__ out) {
    if (threadIdx.x == 0 && blockIdx.x == 0) {
        float s = 0.0f;
        for (int cc = 0; cc < NCLS; ++cc) s += lossAcc[cc] * (1.0f / (float)(NPT - 1));
        out[0] = s;
    }
}

// ---------------------------------------------------------------------------
// Fallback (ws too small): on-the-fly Prim, 1024 threads/class.
// ---------------------------------------------------------------------------
__global__ __launch_bounds__(1024) void prim_onfly_kernel(const float* __restrict__ x,
                                                          float* __restrict__ loss_out) {
    __shared__ float  redV[2][16];
    __shared__ int    redI[2][16];
    __shared__ float  finV[2];
    __shared__ int    finI[2];
    __shared__ float4 xjs[2][16];

    const int c    = blockIdx.x;
    const int tid  = threadIdx.x;
    const int lane = tid & 63;
    const int wid  = tid >> 6;
    const int v0   = tid * 2;
    const int v1   = tid * 2 + 1;

    float m0 = FINF, m1 = FINF;
    bool  t0 = (v0 == 0);
    bool  t1 = false;

    int   j = 0;
    int   p = 0;
    float loss = 0.0f;

    const float4* xc4 = (const float4*)(x + (size_t)c * NPT * DIM);

    for (int t = 0; t < NPT - 1; ++t) {
        if (tid < 16) xjs[p][tid] = xc4[(size_t)j * 16 + tid];
        __syncthreads();
        float a0 = 0.0f, a1 = 0.0f;
        #pragma unroll
        for (int k = 0; k < 16; ++k) {
            float4 xj = xjs[p][k];
            float4 q0 = xc4[(size_t)v0 * 16 + k];
            float4 q1 = xc4[(size_t)v1 * 16 + k];
            float dx;
            dx = xj.x - q0.x; a0 = fmaf(dx, dx, a0);
            dx = xj.y - q0.y; a0 = fmaf(dx, dx, a0);
            dx = xj.z - q0.z; a0 = fmaf(dx, dx, a0);
            dx = xj.w - q0.w; a0 = fmaf(dx, dx, a0);
            dx = xj.x - q1.x; a1 = fmaf(dx, dx, a1);
            dx = xj.y - q1.y; a1 = fmaf(dx, dx, a1);
            dx = xj.z - q1.z; a1 = fmaf(dx, dx, a1);
            dx = xj.w - q1.w; a1 = fmaf(dx, dx, a1);
        }
        float d0 = a0 > 0.0f ? sqrtf(a0) : 0.0f;
        float d1 = a1 > 0.0f ? sqrtf(a1) : 0.0f;

        if (!t0) m0 = fminf(m0, d0);
        if (!t1) m1 = fminf(m1, d1);

        float val; int idx;
        if (m0 <= m1) { val = m0; idx = v0; }
        else          { val = m1; idx = v1; }

        #pragma unroll
        for (int m = 32; m >= 1; m >>= 1) {
            float ov = __shfl_xor(val, m);
            int   oi = __shfl_xor(idx, m);
            if (ov < val || (ov == val && oi < idx)) { val = ov; idx = oi; }
        }
        if (lane == 0) { redV[p][wid] = val; redI[p][wid] = idx; }
        __syncthreads();

        if (wid == 0) {
            float v  = (lane < 16) ? redV[p][lane] : FINF;
            int   i2 = (lane < 16) ? redI[p][lane] : 0x7fffffff;
            #pragma unroll
            for (int m = 8; m >= 1; m >>= 1) {
                float ov = __shfl_xor(v, m);
                int   oi = __shfl_xor(i2, m);
                if (ov < v || (ov == v && oi < i2)) { v = ov; i2 = oi; }
            }
            if (lane == 0) { finV[p] = v; finI[p] = i2; }
        }
        __syncthreads();

        float bv = finV[p];
        j        = finI[p];
        if (tid == 0) loss += fabsf(bv - 1.0f);
        if (v0 == j) { t0 = true; m0 = FINF; }
        if (v1 == j) { t1 = true; m1 = FINF; }
        p ^= 1;
    }

    if (tid == 0) loss_out[c] = loss / (float)(NPT - 1);
}

__global__ void finalize_kernel(const float* __restrict__ loss, float* __restrict__ out) {
    if (threadIdx.x == 0 && blockIdx.x == 0) {
        float s = 0.0f;
        for (int c = 0; c < NCLS; ++c) s += loss[c];
        out[0] = s;
    }
}

extern "C" void kernel_launch(void* const* d_in, const int* in_sizes, int n_in,
                              void* d_out, int out_size, void* d_ws, size_t ws_size,
                              hipStream_t stream) {
    const float* x   = (const float*)d_in[0];
    float*       out = (float*)d_out;

    const size_t distElems = (size_t)NCLS * NPT * NPT;   // u32
    const size_t nv        = (size_t)NCLS * NPT;

    const size_t off_dist  = 0;
    const size_t off_me    = off_dist + distElems * sizeof(u32);      // u64, 8-aligned
    const size_t off_sq    = off_me + nv * sizeof(u64);
    const size_t off_comp  = off_sq + nv * sizeof(float);
    const size_t off_loss  = off_comp + nv * sizeof(u32);
    const size_t off_done  = off_loss + NCLS * sizeof(float);
    const size_t need      = off_done + NCLS * sizeof(u32);

    if (ws_size >= need) {
        u32*   dist     = (u32*)((char*)d_ws + off_dist);
        u64*   minEdge  = (u64*)((char*)d_ws + off_me);
        float* sq       = (float*)((char*)d_ws + off_sq);
        u32*   comp     = (u32*)((char*)d_ws + off_comp);
        float* lossAcc  = (float*)((char*)d_ws + off_loss);
        u32*   done     = (u32*)((char*)d_ws + off_done);

        init_kernel<<<(int)((nv + 255) / 256), 256, 0, stream>>>(comp, minEdge, lossAcc, done);
        row_norms_kernel<<<(NCLS * NPT) / 4, 256, 0, stream>>>(x, sq);
        distkey_kernel<<<dim3(NPT / 64, NPT / 64, NCLS), 256, 0, stream>>>(x, sq, dist, minEdge);
        merge_kernel<<<NCLS, 256, 0, stream>>>(comp, minEdge, lossAcc, done);   // round 1
        for (int r = 0; r < 10; ++r) {                                          // rounds 2..11
            scan_kernel<<<dim3(NPT / 32, NCLS), 256, 0, stream>>>(dist, comp, minEdge, done);
            merge_kernel<<<NCLS, 256, 0, stream>>>(comp, minEdge, lossAcc, done);
        }
        final2_kernel<<<1, 64, 0, stream>>>(lossAcc, out);
    } else {
        float* loss = (float*)d_ws;
        prim_onfly_kernel<<<NCLS, 1024, 0, stream>>>(x, loss);
        finalize_kernel<<<1, 64, 0, stream>>>(loss, out);
    }
}